// Round 9
// baseline (479.405 us; speedup 1.0000x reference)
//
#include <hip/hip_runtime.h>
#include <hip/hip_fp16.h>

// ---------------------------------------------------------------------------
// 2-layer GAT + classifier.
// CSR via two-level multisplit (no random 4B global writes).
// GEMM: f16 MFMA (mfma_f32_16x16x32_f16, fp32 accum), XOR-swizzled LDS,
// fused attention logits + fp16 feature mirror.
// Aggregate: single fused pass, in-loop denominator, 8-deep gather pipeline.
// ---------------------------------------------------------------------------

typedef _Float16 f16;
typedef f16 f16x8 __attribute__((ext_vector_type(8)));
typedef float f32x4 __attribute__((ext_vector_type(4)));

__device__ __forceinline__ float leaky02(float v) { return v > 0.f ? v : 0.2f * v; }

struct h2x2 { __half2 a, b; };  // 8-byte packed 4x fp16

// LDS bank-conflict swizzle: flip half-index bits 3-5 by row (G4 idiom).
#define SWZ(rowv, colv) ((colv) ^ (((rowv) & 7) << 3))

#define NPB 1024          // nodes per bucket (bucket id = dst >> 10)
#define MAXNB 128         // max buckets (N <= 131072)
#define EPT 16            // edges per thread in bucketize
#define CH 4096           // edges per block (256 * EPT)

// ---- pass 1: multisplit edges (+self-loops) into padded bucket regions ----
__global__ __launch_bounds__(256) void k_bucketize(const int* __restrict__ ei,
                                                   uint2* __restrict__ ebuf,
                                                   int* __restrict__ bcur,
                                                   int E, int N, int NB, int region) {
  __shared__ int hist[MAXNB];
  __shared__ int lbase[MAXNB];
  const int t = threadIdx.x;
  const int base = blockIdx.x * CH;
  const int Ep = E + N;
  if (t < MAXNB) hist[t] = 0;
  __syncthreads();
  int src[EPT], dst[EPT];
#pragma unroll
  for (int k = 0; k < EPT; ++k) {
    int e = base + k * 256 + t;
    if (e < E) { src[k] = ei[e]; dst[k] = ei[E + e]; }
    else if (e < Ep) { src[k] = dst[k] = e - E; }   // self-loop
    else { src[k] = -1; dst[k] = -1; }
    if (dst[k] >= 0) atomicAdd(&hist[dst[k] >> 10], 1);
  }
  __syncthreads();
  if (t < NB && hist[t] > 0) lbase[t] = atomicAdd(&bcur[t], hist[t]);
  __syncthreads();
  if (t < MAXNB) hist[t] = 0;   // reuse as local cursor
  __syncthreads();
#pragma unroll
  for (int k = 0; k < EPT; ++k) {
    if (dst[k] >= 0) {
      int b = dst[k] >> 10;
      int r = atomicAdd(&hist[b], 1);
      ebuf[(size_t)b * region + lbase[b] + r] =
          make_uint2((unsigned)src[k], (unsigned)dst[k]);
    }
  }
}

// ---- pass 2: per-bucket CSR (bucket-count scan done redundantly in-block) --
__global__ __launch_bounds__(256) void k_csr(const uint2* __restrict__ ebuf,
                                             const int* __restrict__ bcur,
                                             int* __restrict__ rowptr,
                                             int* __restrict__ colsrc,
                                             int N, int NB, int region) {
  __shared__ int cnt[NPB];
  __shared__ int lds2[256];
  __shared__ int sscan[MAXNB];
  const int b = blockIdx.x;
  const int t = threadIdx.x;
  if (t < MAXNB) sscan[t] = (t < NB) ? bcur[t] : 0;
  __syncthreads();
  for (int off = 1; off < MAXNB; off <<= 1) {
    int u = (t < MAXNB && t >= off) ? sscan[t - off] : 0;
    __syncthreads();
    if (t < MAXNB) sscan[t] += u;
    __syncthreads();
  }
  const int cb = (b == 0) ? 0 : sscan[b - 1];
  if (b == 0 && t == 0) rowptr[N] = sscan[NB - 1];
  const int m = bcur[b];
  const size_t ebase = (size_t)b * region;
#pragma unroll
  for (int i = 0; i < 4; ++i) cnt[t * 4 + i] = 0;
  __syncthreads();
  for (int j = t; j < m; j += 256) {
    int d = (int)(ebuf[ebase + j].y) & (NPB - 1);
    atomicAdd(&cnt[d], 1);
  }
  __syncthreads();
  int v[4], s = 0;
#pragma unroll
  for (int i = 0; i < 4; ++i) { v[i] = cnt[t * 4 + i]; s += v[i]; }
  lds2[t] = s;
  __syncthreads();
  for (int off = 1; off < 256; off <<= 1) {
    int u = (t >= off) ? lds2[t - off] : 0;
    __syncthreads();
    lds2[t] += u;
    __syncthreads();
  }
  int e = lds2[t] - s;  // exclusive over this bucket
  const int node0 = (b << 10) + t * 4;
#pragma unroll
  for (int i = 0; i < 4; ++i) {
    cnt[t * 4 + i] = e;                       // per-node cursor start
    if (node0 + i < N) rowptr[node0 + i] = cb + e;
    e += v[i];
  }
  __syncthreads();
  for (int j = t; j < m; j += 256) {
    uint2 q = ebuf[ebase + j];
    int d = (int)q.y & (NPB - 1);
    int r = atomicAdd(&cnt[d], 1);
    colsrc[cb + r] = (int)q.x;
  }
}

// ---------------- f16 MFMA GEMM: h = A @ W, 64 rows/block ---------------------
// Fuses: fp16 feature mirror (Hh) + per-row/head attention logits (as/ad).
// LDS layout XOR-swizzled (SWZ) on both write and read -> conflict-free b128.
template <int AFP16>
__global__ __launch_bounds__(256) void k_gemm_mfma(const void* __restrict__ Ain,
                                                   const float* __restrict__ W,
                                                   const float* __restrict__ avs,
                                                   const float* __restrict__ avd,
                                                   __half* __restrict__ Hh,
                                                   float* __restrict__ as_out,
                                                   float* __restrict__ ad_out,
                                                   int nrows) {
  __shared__ __align__(16) f16 sA[64][136];    // stride 272 B (16B-mult)
  __shared__ __align__(16) f16 sBT[128][136];  // W^T: [n][k]
  const int t = threadIdx.x;
  const int row0 = blockIdx.x * 64;
  // stage W^T (f16): read W[k][n..n+3] coalesced, scatter-write transpose
#pragma unroll
  for (int i = 0; i < 16; ++i) {
    int idx = (t + i * 256) * 4;
    int k = idx >> 7, n = idx & 127;
    float4 w4 = *(const float4*)&W[idx];
    sBT[n + 0][SWZ(n + 0, k)] = (f16)w4.x;
    sBT[n + 1][SWZ(n + 1, k)] = (f16)w4.y;
    sBT[n + 2][SWZ(n + 2, k)] = (f16)w4.z;
    sBT[n + 3][SWZ(n + 3, k)] = (f16)w4.w;
  }
  // stage A rows (zero-fill out-of-range)
  if (AFP16) {
    const __half* A = (const __half*)Ain + (size_t)row0 * 128;
#pragma unroll
    for (int i = 0; i < 8; ++i) {
      int idx = (t + i * 256) * 4;  // half index
      int m = idx >> 7, c = idx & 127;
      h2x2 v;
      if (row0 + m < nrows) v = *(const h2x2*)&A[idx];
      else { v.a = __floats2half2_rn(0.f, 0.f); v.b = v.a; }
      *(h2x2*)&sA[m][SWZ(m, c)] = v;
    }
  } else {
    const float* A = (const float*)Ain + (size_t)row0 * 128;
#pragma unroll
    for (int i = 0; i < 8; ++i) {
      int idx = (t + i * 256) * 4;  // float index
      int m = idx >> 7, c = idx & 127;
      float4 a4 = (row0 + m < nrows) ? *(const float4*)&A[idx]
                                     : make_float4(0.f, 0.f, 0.f, 0.f);
      h2x2 v;
      v.a = __floats2half2_rn(a4.x, a4.y);
      v.b = __floats2half2_rn(a4.z, a4.w);
      *(h2x2*)&sA[m][SWZ(m, c)] = v;
    }
  }
  __syncthreads();
  const int wv = t >> 6;
  const int l = t & 63;
  const int lm = l & 15;           // m (A-row) / n (B-col, D-col) within tile
  const int lk = (l >> 4) * 8;     // k offset within 32-chunk
  const int mw = wv * 16;          // wave row offset
  f32x4 acc[8];
#pragma unroll
  for (int tt = 0; tt < 8; ++tt) acc[tt] = (f32x4){0.f, 0.f, 0.f, 0.f};
#pragma unroll
  for (int kb = 0; kb < 4; ++kb) {
    const int ar = mw + lm;
    f16x8 af = *(const f16x8*)&sA[ar][SWZ(ar, kb * 32 + lk)];
#pragma unroll
    for (int tt = 0; tt < 8; ++tt) {
      const int br = tt * 16 + lm;
      f16x8 bf = *(const f16x8*)&sBT[br][SWZ(br, kb * 32 + lk)];
      acc[tt] = __builtin_amdgcn_mfma_f32_16x16x32_f16(af, bf, acc[tt], 0, 0, 0);
    }
  }
  // epilogue: attention logit partials + fp16 h store
  float avst[8], avdt[8];
#pragma unroll
  for (int tt = 0; tt < 8; ++tt) {
    avst[tt] = avs[tt * 16 + lm];
    avdt[tt] = avd[tt * 16 + lm];
  }
#pragma unroll
  for (int reg = 0; reg < 4; ++reg) {
    const int row = row0 + mw + (l >> 4) * 4 + reg;
    float ps0 = acc[0][reg] * avst[0] + acc[1][reg] * avst[1];
    float ps1 = acc[2][reg] * avst[2] + acc[3][reg] * avst[3];
    float ps2 = acc[4][reg] * avst[4] + acc[5][reg] * avst[5];
    float ps3 = acc[6][reg] * avst[6] + acc[7][reg] * avst[7];
    float pd0 = acc[0][reg] * avdt[0] + acc[1][reg] * avdt[1];
    float pd1 = acc[2][reg] * avdt[2] + acc[3][reg] * avdt[3];
    float pd2 = acc[4][reg] * avdt[4] + acc[5][reg] * avdt[5];
    float pd3 = acc[6][reg] * avdt[6] + acc[7][reg] * avdt[7];
#pragma unroll
    for (int off = 1; off < 16; off <<= 1) {  // reduce cols within 16-lane group
      ps0 += __shfl_xor(ps0, off); ps1 += __shfl_xor(ps1, off);
      ps2 += __shfl_xor(ps2, off); ps3 += __shfl_xor(ps3, off);
      pd0 += __shfl_xor(pd0, off); pd1 += __shfl_xor(pd1, off);
      pd2 += __shfl_xor(pd2, off); pd3 += __shfl_xor(pd3, off);
    }
    if (row < nrows) {
      if (lm < 4) {
        float vs = lm == 0 ? ps0 : lm == 1 ? ps1 : lm == 2 ? ps2 : ps3;
        float vd = lm == 0 ? pd0 : lm == 1 ? pd1 : lm == 2 ? pd2 : pd3;
        as_out[row * 4 + lm] = vs;
        ad_out[row * 4 + lm] = vd;
      }
#pragma unroll
      for (int tt = 0; tt < 8; ++tt)
        Hh[(size_t)row * 128 + tt * 16 + lm] = __float2half(acc[tt][reg]);
    }
  }
}

// ---------------- fused softmax+aggregate; 32 lanes per node -----------------
// 8-deep gather pipeline. LAYER 1: relu(agg+b1) -> fp16 [N,128];
// LAYER 2: head-mean + b2 + relu + classifier -> out [N,16] fp32.
template <int LAYER>
__global__ __launch_bounds__(256) void k_agg(const int* __restrict__ rowptr,
                                             const int* __restrict__ colsrc,
                                             const float* __restrict__ as,
                                             const float* __restrict__ ad,
                                             const __half* __restrict__ Hh,
                                             const float* __restrict__ b1,
                                             const float* __restrict__ b2,
                                             const float* __restrict__ Wc,
                                             const float* __restrict__ bc,
                                             __half* __restrict__ outh,
                                             float* __restrict__ out, int n) {
  __shared__ float sbuf[8][128];
  const int slot = threadIdx.x >> 5;
  const int l = threadIdx.x & 31;
  const int node = blockIdx.x * 8 + slot;
  const bool active = node < n;
  int start = 0, end = 0;
  float4 adv = make_float4(0.f, 0.f, 0.f, 0.f);
  if (active) {
    start = rowptr[node];
    end = rowptr[node + 1];
    adv = *(const float4*)&ad[node * 4];
  }
  const int hd = l >> 3;
  const float adh = hd == 0 ? adv.x : hd == 1 ? adv.y : hd == 2 ? adv.z : adv.w;
  const int c = l * 4;
  float4 acc = make_float4(0.f, 0.f, 0.f, 0.f);
  float dsum = 0.f;
  int e = start;
  for (; e + 7 < end; e += 8) {  // unroll x8: eight independent gather chains
    int sidx[8];
#pragma unroll
    for (int i = 0; i < 8; ++i) sidx[i] = colsrc[e + i];
    float av[8];
    h2x2 q[8];
#pragma unroll
    for (int i = 0; i < 8; ++i) {
      av[i] = as[sidx[i] * 4 + hd];
      q[i] = *(const h2x2*)&Hh[(size_t)sidx[i] * 128 + c];
    }
#pragma unroll
    for (int i = 0; i < 8; ++i) {
      float w = __expf(leaky02(av[i] + adh));
      dsum += w;
      float2 fa = __half22float2(q[i].a), fb = __half22float2(q[i].b);
      acc.x = fmaf(w, fa.x, acc.x); acc.y = fmaf(w, fa.y, acc.y);
      acc.z = fmaf(w, fb.x, acc.z); acc.w = fmaf(w, fb.y, acc.w);
    }
  }
  for (; e < end; ++e) {
    int s0 = colsrc[e];
    float w = __expf(leaky02(as[s0 * 4 + hd] + adh));
    h2x2 q = *(const h2x2*)&Hh[(size_t)s0 * 128 + c];
    float2 fa = __half22float2(q.a), fb = __half22float2(q.b);
    dsum += w;
    acc.x = fmaf(w, fa.x, acc.x); acc.y = fmaf(w, fa.y, acc.y);
    acc.z = fmaf(w, fb.x, acc.z); acc.w = fmaf(w, fb.y, acc.w);
  }
  const float inv = dsum > 0.f ? 1.0f / dsum : 0.f;
  acc.x *= inv; acc.y *= inv; acc.z *= inv; acc.w *= inv;
  if (LAYER == 1) {
    if (active) {
      float4 bv = *(const float4*)&b1[c];
      h2x2 pk;
      pk.a = __floats2half2_rn(fmaxf(acc.x + bv.x, 0.f), fmaxf(acc.y + bv.y, 0.f));
      pk.b = __floats2half2_rn(fmaxf(acc.z + bv.z, 0.f), fmaxf(acc.w + bv.w, 0.f));
      *(h2x2*)&outh[(size_t)node * 128 + c] = pk;
    }
  } else {
    *(float4*)&sbuf[slot][c] = acc;
    __syncthreads();
    float f = 0.25f * (sbuf[slot][l] + sbuf[slot][l + 32] +
                       sbuf[slot][l + 64] + sbuf[slot][l + 96]);
    f = fmaxf(f + b2[l], 0.f);
    __syncthreads();
    sbuf[slot][l] = f;
    __syncthreads();
    if (active && l < 16) {
      float o = bc[l];
#pragma unroll
      for (int cc = 0; cc < 32; ++cc) o = fmaf(sbuf[slot][cc], Wc[cc * 16 + l], o);
      out[(size_t)node * 16 + l] = o;
    }
  }
}

// ---------------------------------------------------------------------------
extern "C" void kernel_launch(void* const* d_in, const int* in_sizes, int n_in,
                              void* d_out, int out_size, void* d_ws, size_t ws_size,
                              hipStream_t stream) {
  const float* x = (const float*)d_in[0];
  const int* ei = (const int*)d_in[1];   // [2,E] int32
  const float* W1 = (const float*)d_in[2];
  const float* a_s1 = (const float*)d_in[3];
  const float* a_d1 = (const float*)d_in[4];
  const float* b1 = (const float*)d_in[5];
  const float* W2 = (const float*)d_in[6];
  const float* a_s2 = (const float*)d_in[7];
  const float* a_d2 = (const float*)d_in[8];
  const float* b2 = (const float*)d_in[9];
  const float* Wc = (const float*)d_in[10];
  const float* bc = (const float*)d_in[11];
  float* out = (float*)d_out;

  const int N = in_sizes[0] / 128;
  const int E = in_sizes[1] / 2;
  const int Ep = E + N;
  const int NB = (N + NPB - 1) >> 10;
  const int region = Ep / NB + 4096;

  // workspace carve-up
  char* p = (char*)d_ws;
  auto align16 = [](char* q) { return (char*)(((uintptr_t)q + 15) & ~(uintptr_t)15); };
  __half* Hh = (__half*)p;   p = align16(p + sizeof(__half) * (size_t)N * 128);
  __half* x2h = (__half*)p;  p = align16(p + sizeof(__half) * (size_t)N * 128);
  float* asb = (float*)p;    p = align16(p + sizeof(float) * (size_t)N * 4);
  float* adb = (float*)p;    p = align16(p + sizeof(float) * (size_t)N * 4);
  int* rowptr = (int*)p;     p = align16(p + sizeof(int) * (size_t)(N + 1));
  int* bcur = (int*)p;       p = align16(p + sizeof(int) * MAXNB);
  int* colsrc = (int*)p;     p = align16(p + sizeof(int) * (size_t)Ep);
  uint2* ebuf = (uint2*)p;   // NB * region * 8B (~17 MB)

  hipMemsetAsync(bcur, 0, sizeof(int) * MAXNB, stream);

  k_bucketize<<<(Ep + CH - 1) / CH, 256, 0, stream>>>(ei, ebuf, bcur, E, N, NB, region);
  k_csr<<<NB, 256, 0, stream>>>(ebuf, bcur, rowptr, colsrc, N, NB, region);

  const int gblocks = (N + 63) / 64;
  k_gemm_mfma<0><<<gblocks, 256, 0, stream>>>(x, W1, a_s1, a_d1, Hh, asb, adb, N);
  k_agg<1><<<(N + 7) / 8, 256, 0, stream>>>(rowptr, colsrc, asb, adb, Hh,
                                            b1, nullptr, nullptr, nullptr, x2h, nullptr, N);
  k_gemm_mfma<1><<<gblocks, 256, 0, stream>>>(x2h, W2, a_s2, a_d2, Hh, asb, adb, N);
  k_agg<2><<<(N + 7) / 8, 256, 0, stream>>>(rowptr, colsrc, asb, adb, Hh,
                                            nullptr, b2, Wc, bc, nullptr, out, N);
}

// Round 12
// 383.680 us; speedup vs baseline: 1.2495x; 1.2495x over previous
//
#include <hip/hip_runtime.h>
#include <hip/hip_fp16.h>

// ---------------------------------------------------------------------------
// 2-layer GAT + classifier.
// CSR via two-level multisplit. GEMM: f16 MFMA, 128-row tiles, W pre-transposed
// (k_prep) so LDS staging is straight vector copies (R9 lesson: the transpose
// scatter was a 32-way bank conflict; fragment reads were already fine).
// Aggregate: R8's 4-deep gather pipeline (R9 lesson: 8-deep costs occupancy).
// ---------------------------------------------------------------------------

typedef _Float16 f16;
typedef f16 f16x8 __attribute__((ext_vector_type(8)));
typedef float f32x4 __attribute__((ext_vector_type(4)));

__device__ __forceinline__ float leaky02(float v) { return v > 0.f ? v : 0.2f * v; }

struct h2x2 { __half2 a, b; };  // 8-byte packed 4x fp16

#define NPB 1024
#define MAXNB 128
#define EPT 16
#define CH 4096

// ---- pass 1: multisplit edges (+self-loops) into padded bucket regions ----
__global__ __launch_bounds__(256) void k_bucketize(const int* __restrict__ ei,
                                                   uint2* __restrict__ ebuf,
                                                   int* __restrict__ bcur,
                                                   int E, int N, int NB, int region) {
  __shared__ int hist[MAXNB];
  __shared__ int lbase[MAXNB];
  const int t = threadIdx.x;
  const int base = blockIdx.x * CH;
  const int Ep = E + N;
  if (t < MAXNB) hist[t] = 0;
  __syncthreads();
  int src[EPT], dst[EPT];
#pragma unroll
  for (int k = 0; k < EPT; ++k) {
    int e = base + k * 256 + t;
    if (e < E) { src[k] = ei[e]; dst[k] = ei[E + e]; }
    else if (e < Ep) { src[k] = dst[k] = e - E; }
    else { src[k] = -1; dst[k] = -1; }
    if (dst[k] >= 0) atomicAdd(&hist[dst[k] >> 10], 1);
  }
  __syncthreads();
  if (t < NB && hist[t] > 0) lbase[t] = atomicAdd(&bcur[t], hist[t]);
  __syncthreads();
  if (t < MAXNB) hist[t] = 0;
  __syncthreads();
#pragma unroll
  for (int k = 0; k < EPT; ++k) {
    if (dst[k] >= 0) {
      int b = dst[k] >> 10;
      int r = atomicAdd(&hist[b], 1);
      ebuf[(size_t)b * region + lbase[b] + r] =
          make_uint2((unsigned)src[k], (unsigned)dst[k]);
    }
  }
}

// ---- pass 2: per-bucket CSR ------------------------------------------------
__global__ __launch_bounds__(256) void k_csr(const uint2* __restrict__ ebuf,
                                             const int* __restrict__ bcur,
                                             int* __restrict__ rowptr,
                                             int* __restrict__ colsrc,
                                             int N, int NB, int region) {
  __shared__ int cnt[NPB];
  __shared__ int lds2[256];
  __shared__ int sscan[MAXNB];
  const int b = blockIdx.x;
  const int t = threadIdx.x;
  if (t < MAXNB) sscan[t] = (t < NB) ? bcur[t] : 0;
  __syncthreads();
  for (int off = 1; off < MAXNB; off <<= 1) {
    int u = (t < MAXNB && t >= off) ? sscan[t - off] : 0;
    __syncthreads();
    if (t < MAXNB) sscan[t] += u;
    __syncthreads();
  }
  const int cb = (b == 0) ? 0 : sscan[b - 1];
  if (b == 0 && t == 0) rowptr[N] = sscan[NB - 1];
  const int m = bcur[b];
  const size_t ebase = (size_t)b * region;
#pragma unroll
  for (int i = 0; i < 4; ++i) cnt[t * 4 + i] = 0;
  __syncthreads();
  for (int j = t; j < m; j += 256) {
    int d = (int)(ebuf[ebase + j].y) & (NPB - 1);
    atomicAdd(&cnt[d], 1);
  }
  __syncthreads();
  int v[4], s = 0;
#pragma unroll
  for (int i = 0; i < 4; ++i) { v[i] = cnt[t * 4 + i]; s += v[i]; }
  lds2[t] = s;
  __syncthreads();
  for (int off = 1; off < 256; off <<= 1) {
    int u = (t >= off) ? lds2[t - off] : 0;
    __syncthreads();
    lds2[t] += u;
    __syncthreads();
  }
  int e = lds2[t] - s;
  const int node0 = (b << 10) + t * 4;
#pragma unroll
  for (int i = 0; i < 4; ++i) {
    cnt[t * 4 + i] = e;
    if (node0 + i < N) rowptr[node0 + i] = cb + e;
    e += v[i];
  }
  __syncthreads();
  for (int j = t; j < m; j += 256) {
    uint2 q = ebuf[ebase + j];
    int d = (int)q.y & (NPB - 1);
    int r = atomicAdd(&cnt[d], 1);
    colsrc[cb + r] = (int)q.x;
  }
}

// ---- W pre-transpose: Wt[n][k] = (f16)W[k][n], 128x128 ---------------------
__global__ __launch_bounds__(256) void k_prep(const float* __restrict__ W,
                                              f16* __restrict__ Wt) {
  int t = threadIdx.x;
  int n = blockIdx.x * 2 + (t >> 7);
  int k = t & 127;
  Wt[n * 128 + k] = (f16)W[k * 128 + n];
}

// ---------------- f16 MFMA GEMM: h = A @ W, 128 rows/block -------------------
// Wave w owns rows [w*32, w*32+32): 2 m-tiles x 8 n-tiles x 4 K-steps = 64 MFMA.
// Staging: straight 16B copies (Wt pre-transposed). Hh store via LDS bounce.
template <int AFP16>
__global__ __launch_bounds__(256) void k_gemm_mfma(const void* __restrict__ Ain,
                                                   const f16* __restrict__ Wt,
                                                   const float* __restrict__ avs,
                                                   const float* __restrict__ avd,
                                                   __half* __restrict__ Hh,
                                                   float* __restrict__ as_out,
                                                   float* __restrict__ ad_out,
                                                   int nrows) {
  __shared__ __align__(16) f16 sA[128][136];   // row stride 272B (16B-mult)
  __shared__ __align__(16) f16 sBT[128][136];  // Wt: [n][k]
  const int t = threadIdx.x;
  const int row0 = blockIdx.x * 128;
  // stage Wt: 2048 16B chunks, coalesced, <=2-way LDS banks
#pragma unroll
  for (int i = 0; i < 8; ++i) {
    int q = t + i * 256;
    int n = q >> 4, kc = q & 15;
    *(uint4*)&sBT[n][kc * 8] = *(const uint4*)&Wt[n * 128 + kc * 8];
  }
  // stage A rows (zero-fill out-of-range)
  if (AFP16) {
    const __half* A = (const __half*)Ain;
#pragma unroll
    for (int i = 0; i < 8; ++i) {
      int q = t + i * 256;
      int m = q >> 4, kc = q & 15;
      uint4 v = make_uint4(0u, 0u, 0u, 0u);
      if (row0 + m < nrows) v = *(const uint4*)&A[(size_t)(row0 + m) * 128 + kc * 8];
      *(uint4*)&sA[m][kc * 8] = v;
    }
  } else {
    const float* A = (const float*)Ain;
#pragma unroll
    for (int i = 0; i < 16; ++i) {
      int q = t + i * 256;
      int m = q >> 5, c4 = (q & 31) * 4;
      float4 a4 = (row0 + m < nrows) ? *(const float4*)&A[(size_t)(row0 + m) * 128 + c4]
                                     : make_float4(0.f, 0.f, 0.f, 0.f);
      h2x2 v;
      v.a = __floats2half2_rn(a4.x, a4.y);
      v.b = __floats2half2_rn(a4.z, a4.w);
      *(h2x2*)&sA[m][c4] = v;
    }
  }
  __syncthreads();
  const int wv = t >> 6;
  const int l = t & 63;
  const int lm = l & 15;
  const int lk = (l >> 4) * 8;
  const int mw = wv * 32;
  f32x4 acc[2][8];
#pragma unroll
  for (int mt = 0; mt < 2; ++mt)
#pragma unroll
    for (int tt = 0; tt < 8; ++tt) acc[mt][tt] = (f32x4){0.f, 0.f, 0.f, 0.f};
#pragma unroll
  for (int kb = 0; kb < 4; ++kb) {
    f16x8 af0 = *(const f16x8*)&sA[mw + lm][kb * 32 + lk];
    f16x8 af1 = *(const f16x8*)&sA[mw + 16 + lm][kb * 32 + lk];
#pragma unroll
    for (int tt = 0; tt < 8; ++tt) {
      f16x8 bf = *(const f16x8*)&sBT[tt * 16 + lm][kb * 32 + lk];
      acc[0][tt] = __builtin_amdgcn_mfma_f32_16x16x32_f16(af0, bf, acc[0][tt], 0, 0, 0);
      acc[1][tt] = __builtin_amdgcn_mfma_f32_16x16x32_f16(af1, bf, acc[1][tt], 0, 0, 0);
    }
  }
  // epilogue: attention logits via shuffles + Hh via wave-private LDS bounce
  float avst[8], avdt[8];
#pragma unroll
  for (int tt = 0; tt < 8; ++tt) {
    avst[tt] = avs[tt * 16 + lm];
    avdt[tt] = avd[tt * 16 + lm];
  }
#pragma unroll
  for (int mt = 0; mt < 2; ++mt) {
#pragma unroll
    for (int reg = 0; reg < 4; ++reg) {
      const int row = row0 + mw + mt * 16 + (l >> 4) * 4 + reg;
      float ps0 = acc[mt][0][reg] * avst[0] + acc[mt][1][reg] * avst[1];
      float ps1 = acc[mt][2][reg] * avst[2] + acc[mt][3][reg] * avst[3];
      float ps2 = acc[mt][4][reg] * avst[4] + acc[mt][5][reg] * avst[5];
      float ps3 = acc[mt][6][reg] * avst[6] + acc[mt][7][reg] * avst[7];
      float pd0 = acc[mt][0][reg] * avdt[0] + acc[mt][1][reg] * avdt[1];
      float pd1 = acc[mt][2][reg] * avdt[2] + acc[mt][3][reg] * avdt[3];
      float pd2 = acc[mt][4][reg] * avdt[4] + acc[mt][5][reg] * avdt[5];
      float pd3 = acc[mt][6][reg] * avdt[6] + acc[mt][7][reg] * avdt[7];
#pragma unroll
      for (int off = 1; off < 16; off <<= 1) {
        ps0 += __shfl_xor(ps0, off); ps1 += __shfl_xor(ps1, off);
        ps2 += __shfl_xor(ps2, off); ps3 += __shfl_xor(ps3, off);
        pd0 += __shfl_xor(pd0, off); pd1 += __shfl_xor(pd1, off);
        pd2 += __shfl_xor(pd2, off); pd3 += __shfl_xor(pd3, off);
      }
      if (row < nrows && lm < 4) {
        float vs = lm == 0 ? ps0 : lm == 1 ? ps1 : lm == 2 ? ps2 : ps3;
        float vd = lm == 0 ? pd0 : lm == 1 ? pd1 : lm == 2 ? pd2 : pd3;
        as_out[row * 4 + lm] = vs;
        ad_out[row * 4 + lm] = vd;
      }
      // bounce into own wave's sA region (wave-private rows -> no barrier)
      const int lr = mw + mt * 16 + (l >> 4) * 4 + reg;
#pragma unroll
      for (int tt = 0; tt < 8; ++tt) sA[lr][tt * 16 + lm] = (f16)acc[mt][tt][reg];
    }
  }
  // coalesced Hh store from bounce buffer: 512 chunks/wave, 8 per lane
#pragma unroll
  for (int i = 0; i < 8; ++i) {
    int q = l + i * 64;
    int m = mw + (q >> 4), kc = q & 15;
    int row = row0 + m;
    if (row < nrows)
      *(uint4*)&Hh[(size_t)row * 128 + kc * 8] = *(const uint4*)&sA[m][kc * 8];
  }
}

// ---------------- fused softmax+aggregate (R8 form, 4-deep) ------------------
template <int LAYER>
__global__ __launch_bounds__(256) void k_agg(const int* __restrict__ rowptr,
                                             const int* __restrict__ colsrc,
                                             const float* __restrict__ as,
                                             const float* __restrict__ ad,
                                             const __half* __restrict__ Hh,
                                             const float* __restrict__ b1,
                                             const float* __restrict__ b2,
                                             const float* __restrict__ Wc,
                                             const float* __restrict__ bc,
                                             __half* __restrict__ outh,
                                             float* __restrict__ out, int n) {
  __shared__ float sbuf[8][128];
  const int slot = threadIdx.x >> 5;
  const int l = threadIdx.x & 31;
  const int node = blockIdx.x * 8 + slot;
  const bool active = node < n;
  int start = 0, end = 0;
  float4 adv = make_float4(0.f, 0.f, 0.f, 0.f);
  if (active) {
    start = rowptr[node];
    end = rowptr[node + 1];
    adv = *(const float4*)&ad[node * 4];
  }
  const int hd = l >> 3;
  const float adh = hd == 0 ? adv.x : hd == 1 ? adv.y : hd == 2 ? adv.z : adv.w;
  const int c = l * 4;
  float4 acc = make_float4(0.f, 0.f, 0.f, 0.f);
  float dsum = 0.f;
  int e = start;
  for (; e + 3 < end; e += 4) {
    int s0 = colsrc[e], s1 = colsrc[e + 1], s2 = colsrc[e + 2], s3 = colsrc[e + 3];
    float a0 = as[s0 * 4 + hd];
    float a1 = as[s1 * 4 + hd];
    float a2 = as[s2 * 4 + hd];
    float a3 = as[s3 * 4 + hd];
    h2x2 q0 = *(const h2x2*)&Hh[(size_t)s0 * 128 + c];
    h2x2 q1 = *(const h2x2*)&Hh[(size_t)s1 * 128 + c];
    h2x2 q2 = *(const h2x2*)&Hh[(size_t)s2 * 128 + c];
    h2x2 q3 = *(const h2x2*)&Hh[(size_t)s3 * 128 + c];
    float w0 = __expf(leaky02(a0 + adh));
    float w1 = __expf(leaky02(a1 + adh));
    float w2 = __expf(leaky02(a2 + adh));
    float w3 = __expf(leaky02(a3 + adh));
    dsum += w0 + w1 + w2 + w3;
    float2 f0a = __half22float2(q0.a), f0b = __half22float2(q0.b);
    float2 f1a = __half22float2(q1.a), f1b = __half22float2(q1.b);
    float2 f2a = __half22float2(q2.a), f2b = __half22float2(q2.b);
    float2 f3a = __half22float2(q3.a), f3b = __half22float2(q3.b);
    acc.x = fmaf(w0, f0a.x, acc.x); acc.y = fmaf(w0, f0a.y, acc.y);
    acc.z = fmaf(w0, f0b.x, acc.z); acc.w = fmaf(w0, f0b.y, acc.w);
    acc.x = fmaf(w1, f1a.x, acc.x); acc.y = fmaf(w1, f1a.y, acc.y);
    acc.z = fmaf(w1, f1b.x, acc.z); acc.w = fmaf(w1, f1b.y, acc.w);
    acc.x = fmaf(w2, f2a.x, acc.x); acc.y = fmaf(w2, f2a.y, acc.y);
    acc.z = fmaf(w2, f2b.x, acc.z); acc.w = fmaf(w2, f2b.y, acc.w);
    acc.x = fmaf(w3, f3a.x, acc.x); acc.y = fmaf(w3, f3a.y, acc.y);
    acc.z = fmaf(w3, f3b.x, acc.z); acc.w = fmaf(w3, f3b.y, acc.w);
  }
  for (; e < end; ++e) {
    int s0 = colsrc[e];
    float w = __expf(leaky02(as[s0 * 4 + hd] + adh));
    h2x2 q = *(const h2x2*)&Hh[(size_t)s0 * 128 + c];
    float2 fa = __half22float2(q.a), fb = __half22float2(q.b);
    dsum += w;
    acc.x = fmaf(w, fa.x, acc.x); acc.y = fmaf(w, fa.y, acc.y);
    acc.z = fmaf(w, fb.x, acc.z); acc.w = fmaf(w, fb.y, acc.w);
  }
  const float inv = dsum > 0.f ? 1.0f / dsum : 0.f;
  acc.x *= inv; acc.y *= inv; acc.z *= inv; acc.w *= inv;
  if (LAYER == 1) {
    if (active) {
      float4 bv = *(const float4*)&b1[c];
      h2x2 pk;
      pk.a = __floats2half2_rn(fmaxf(acc.x + bv.x, 0.f), fmaxf(acc.y + bv.y, 0.f));
      pk.b = __floats2half2_rn(fmaxf(acc.z + bv.z, 0.f), fmaxf(acc.w + bv.w, 0.f));
      *(h2x2*)&outh[(size_t)node * 128 + c] = pk;
    }
  } else {
    *(float4*)&sbuf[slot][c] = acc;
    __syncthreads();
    float f = 0.25f * (sbuf[slot][l] + sbuf[slot][l + 32] +
                       sbuf[slot][l + 64] + sbuf[slot][l + 96]);
    f = fmaxf(f + b2[l], 0.f);
    __syncthreads();
    sbuf[slot][l] = f;
    __syncthreads();
    if (active && l < 16) {
      float o = bc[l];
#pragma unroll
      for (int cc = 0; cc < 32; ++cc) o = fmaf(sbuf[slot][cc], Wc[cc * 16 + l], o);
      out[(size_t)node * 16 + l] = o;
    }
  }
}

// ---------------------------------------------------------------------------
extern "C" void kernel_launch(void* const* d_in, const int* in_sizes, int n_in,
                              void* d_out, int out_size, void* d_ws, size_t ws_size,
                              hipStream_t stream) {
  const float* x = (const float*)d_in[0];
  const int* ei = (const int*)d_in[1];
  const float* W1 = (const float*)d_in[2];
  const float* a_s1 = (const float*)d_in[3];
  const float* a_d1 = (const float*)d_in[4];
  const float* b1 = (const float*)d_in[5];
  const float* W2 = (const float*)d_in[6];
  const float* a_s2 = (const float*)d_in[7];
  const float* a_d2 = (const float*)d_in[8];
  const float* b2 = (const float*)d_in[9];
  const float* Wc = (const float*)d_in[10];
  const float* bc = (const float*)d_in[11];
  float* out = (float*)d_out;

  const int N = in_sizes[0] / 128;
  const int E = in_sizes[1] / 2;
  const int Ep = E + N;
  const int NB = (N + NPB - 1) >> 10;
  const int region = Ep / NB + 4096;

  char* p = (char*)d_ws;
  auto align16 = [](char* q) { return (char*)(((uintptr_t)q + 15) & ~(uintptr_t)15); };
  __half* Hh = (__half*)p;   p = align16(p + sizeof(__half) * (size_t)N * 128);
  __half* x2h = (__half*)p;  p = align16(p + sizeof(__half) * (size_t)N * 128);
  float* asb = (float*)p;    p = align16(p + sizeof(float) * (size_t)N * 4);
  float* adb = (float*)p;    p = align16(p + sizeof(float) * (size_t)N * 4);
  int* rowptr = (int*)p;     p = align16(p + sizeof(int) * (size_t)(N + 1));
  int* bcur = (int*)p;       p = align16(p + sizeof(int) * MAXNB);
  f16* Wt = (f16*)p;         p = align16(p + sizeof(f16) * 128 * 128);
  int* colsrc = (int*)p;     p = align16(p + sizeof(int) * (size_t)Ep);
  uint2* ebuf = (uint2*)p;

  hipMemsetAsync(bcur, 0, sizeof(int) * MAXNB, stream);

  k_bucketize<<<(Ep + CH - 1) / CH, 256, 0, stream>>>(ei, ebuf, bcur, E, N, NB, region);
  k_csr<<<NB, 256, 0, stream>>>(ebuf, bcur, rowptr, colsrc, N, NB, region);

  const int gblocks = (N + 127) / 128;
  k_prep<<<64, 256, 0, stream>>>(W1, Wt);
  k_gemm_mfma<0><<<gblocks, 256, 0, stream>>>(x, Wt, a_s1, a_d1, Hh, asb, adb, N);
  k_agg<1><<<(N + 7) / 8, 256, 0, stream>>>(rowptr, colsrc, asb, adb, Hh,
                                            b1, nullptr, nullptr, nullptr, x2h, nullptr, N);
  k_prep<<<64, 256, 0, stream>>>(W2, Wt);
  k_gemm_mfma<1><<<gblocks, 256, 0, stream>>>(x2h, Wt, a_s2, a_d2, Hh, asb, adb, N);
  k_agg<2><<<(N + 7) / 8, 256, 0, stream>>>(rowptr, colsrc, asb, adb, Hh,
                                            nullptr, b2, Wc, bc, nullptr, out, N);
}